// Round 7
// baseline (383.834 us; speedup 1.0000x reference)
//
#include <hip/hip_runtime.h>
#include <hip/hip_bf16.h>

typedef __bf16 bf16;
typedef unsigned short u16;
typedef bf16 bf16x8 __attribute__((ext_vector_type(8)));
typedef bf16 bf16x2 __attribute__((ext_vector_type(2)));
typedef u16  u16x8  __attribute__((ext_vector_type(8)));
typedef u16  u16x4  __attribute__((ext_vector_type(4)));
typedef float f32x4 __attribute__((ext_vector_type(4)));
typedef float f32x16 __attribute__((ext_vector_type(16)));

#define MFMA16(a,b,c) __builtin_amdgcn_mfma_f32_16x16x32_bf16((a),(b),(c),0,0,0)
#define MFMA32(a,b,c) __builtin_amdgcn_mfma_f32_32x32x16_bf16((a),(b),(c),0,0,0)
#define QSCALE 0.09016844005625f   // (1/16) * log2(e)

__device__ inline unsigned pack2(float a, float b) {
    bf16x2 t; t[0] = (bf16)a; t[1] = (bf16)b;
    return __builtin_bit_cast(unsigned, t);
}

// async global->LDS, 16B per lane; LDS dest must be wave-uniform base + lane*16
__device__ __forceinline__ void load_lds16(const void* g, void* l) {
    __builtin_amdgcn_global_load_lds(
        (const __attribute__((address_space(1))) unsigned*)g,
        (__attribute__((address_space(3))) unsigned*)l, 16, 0, 0);
}

// Work items, heavy-first. qt>=8 items are split into two key-chunks:
// ci=0 -> tiles [0,32), ci=1 -> tiles [32, 4*(qt+1)).  672 = 24*28 total.
// pack: qt | ci<<4 | kt1<<5   (kt0 = ci*32)
__device__ const unsigned short g_items[24] = {
    (unsigned short)(15 | (0u<<4) | (32u<<5)),
    (unsigned short)(14 | (0u<<4) | (32u<<5)),
    (unsigned short)(13 | (0u<<4) | (32u<<5)),
    (unsigned short)(12 | (0u<<4) | (32u<<5)),
    (unsigned short)(11 | (0u<<4) | (32u<<5)),
    (unsigned short)(10 | (0u<<4) | (32u<<5)),
    (unsigned short)( 9 | (0u<<4) | (32u<<5)),
    (unsigned short)( 8 | (0u<<4) | (32u<<5)),
    (unsigned short)(15 | (1u<<4) | (64u<<5)),
    (unsigned short)( 7 | (0u<<4) | (32u<<5)),
    (unsigned short)(14 | (1u<<4) | (60u<<5)),
    (unsigned short)( 6 | (0u<<4) | (28u<<5)),
    (unsigned short)(13 | (1u<<4) | (56u<<5)),
    (unsigned short)( 5 | (0u<<4) | (24u<<5)),
    (unsigned short)(12 | (1u<<4) | (52u<<5)),
    (unsigned short)( 4 | (0u<<4) | (20u<<5)),
    (unsigned short)(11 | (1u<<4) | (48u<<5)),
    (unsigned short)( 3 | (0u<<4) | (16u<<5)),
    (unsigned short)(10 | (1u<<4) | (44u<<5)),
    (unsigned short)( 2 | (0u<<4) | (12u<<5)),
    (unsigned short)( 9 | (1u<<4) | (40u<<5)),
    (unsigned short)( 1 | (0u<<4) | ( 8u<<5)),
    (unsigned short)( 8 | (1u<<4) | (36u<<5)),
    (unsigned short)( 0 | (0u<<4) | ( 4u<<5)),
};

// W (f32 [c][d]) -> bf16 transposed [which][d][c]
__global__ void cvt_w(const float* __restrict__ Wq, const float* __restrict__ Wk,
                      const float* __restrict__ Wv, bf16* __restrict__ Wbt,
                      int* __restrict__ cnt) {
    if (blockIdx.x == 0 && threadIdx.x == 0) *cnt = 0;
    int idx = blockIdx.x * 256 + threadIdx.x;
    int which = idx >> 16;
    int rem = idx & 65535;
    int c = rem >> 8, d = rem & 255;
    const float* W = (which == 0) ? Wq : (which == 1) ? Wk : Wv;
    Wbt[(size_t)which * 65536 + d * 256 + c] = (bf16)W[c * 256 + d];
}

// ---------------------------------------------------------------- QKV GEMM
// block = 64 tokens x full 256 d; q/k/v fused. x-tile staged ONCE (both
// K-halves) -- it is identical across q/k/v.  W fragments read directly from
// global (384 KB total, L2-broadcast: each wave-load covers 16 full cache
// lines).  Barriers: 1 (A-stage) + 24 (epilogue) instead of 78.
__global__ __launch_bounds__(256, 2)
void qkv_gemm(const float* __restrict__ x, const bf16* __restrict__ Wbt,
              bf16* __restrict__ Qb, bf16* __restrict__ Kb,
              bf16* __restrict__ Vtt1, bf16* __restrict__ Vtt2, bf16* __restrict__ Vtt4) {
    __shared__ __align__(16) u16 lA[2][64 * 136];   // [kh][tok][col]
    __shared__ __align__(16) u16 lB[64 * 72];       // epilogue staging
    int mt = blockIdx.x;
    int tid = threadIdx.x, wv = tid >> 6, lane = tid & 63;
    int l15 = lane & 15, quad = lane >> 4;

    const float* Ax = x + (size_t)(mt * 64) * 256;
    int row = tid >> 2, c0 = (tid & 3) * 32;

    // stage A (both halves), one barrier
    #pragma unroll
    for (int kh = 0; kh < 2; kh++)
        #pragma unroll
        for (int i = 0; i < 4; i++) {
            float4 f0 = *(const float4*)(Ax + row * 256 + kh * 128 + c0 + i * 8);
            float4 f1 = *(const float4*)(Ax + row * 256 + kh * 128 + c0 + i * 8 + 4);
            bf16x8 v;
            v[0] = (bf16)f0.x; v[1] = (bf16)f0.y; v[2] = (bf16)f0.z; v[3] = (bf16)f0.w;
            v[4] = (bf16)f1.x; v[5] = (bf16)f1.y; v[6] = (bf16)f1.z; v[7] = (bf16)f1.w;
            *(bf16x8*)((bf16*)lA[kh] + row * 136 + c0 + i * 8) = v;
        }
    __syncthreads();

    for (int which = 0; which < 3; which++) {
        f32x4 acc[4][4] = {};
        const bf16* Bw = Wbt + (size_t)which * 65536;

        #pragma unroll
        for (int kh = 0; kh < 2; kh++)
            #pragma unroll
            for (int ks = 0; ks < 4; ks++) {
                bf16x8 a = *(const bf16x8*)((bf16*)lA[kh] + (wv * 16 + l15) * 136 + ks * 32 + quad * 8);
                #pragma unroll
                for (int nt = 0; nt < 4; nt++)
                    #pragma unroll
                    for (int ns = 0; ns < 4; ns++) {
                        bf16x8 b2 = *(const bf16x8*)(Bw + (size_t)(nt * 64 + ns * 16 + l15) * 256
                                                     + kh * 128 + ks * 32 + quad * 8);
                        acc[nt][ns] = MFMA16(a, b2, acc[nt][ns]);
                    }
            }

        // Epilogue per nt, staged through lB for coalesced stores.
        u16* lT = lB;                     // [64][72] u16
        float sc = (which == 0) ? QSCALE : 1.0f;
        for (int nt = 0; nt < 4; nt++) {
            __syncthreads();
            if (which < 2) {
                // layout [tok][col]
                #pragma unroll
                for (int ns = 0; ns < 4; ns++)
                    #pragma unroll
                    for (int r = 0; r < 4; r++) {
                        bf16 v = (bf16)(acc[nt][ns][r] * sc);
                        lT[(wv * 16 + quad * 4 + r) * 72 + ns * 16 + l15] = *(u16*)&v;
                    }
                __syncthreads();
                bf16* outp = (which == 0) ? Qb : Kb;
                int tokl = tid >> 2, ch = tid & 3;
                u16x8 v0 = *(u16x8*)(lT + tokl * 72 + ch * 16);
                u16x8 v1 = *(u16x8*)(lT + tokl * 72 + ch * 16 + 8);
                u16* dst = (u16*)outp + (size_t)(mt * 64 + tokl) * 256 + nt * 64 + ch * 16;
                *(u16x8*)dst = v0;
                *(u16x8*)(dst + 8) = v1;
            } else {
                // layout [col d][tok]
                #pragma unroll
                for (int ns = 0; ns < 4; ns++)
                    #pragma unroll
                    for (int r = 0; r < 4; r++) {
                        bf16 v = (bf16)acc[nt][ns][r];
                        lT[(ns * 16 + l15) * 72 + wv * 16 + quad * 4 + r] = *(u16*)&v;
                    }
                __syncthreads();
                int gtok = mt * 64;
                int bL = gtok >> 13, n0 = gtok & 8191;
                int d_l = tid >> 2, q = tid & 3;
                int dg = nt * 64 + d_l;
                {   // cfg1
                    int s1 = n0 >> 11, j1 = n0 & 2047;
                    u16* dst = (u16*)Vtt1 + ((size_t)(bL * 4 + s1) * 64 + (j1 >> 5) + (q >> 1)) * 8192
                               + (size_t)dg * 32 + (q & 1) * 16;
                    u16x8 a0 = *(u16x8*)(lT + d_l * 72 + q * 16);
                    u16x8 a1 = *(u16x8*)(lT + d_l * 72 + q * 16 + 8);
                    *(u16x8*)dst = a0; *(u16x8*)(dst + 8) = a1;
                }
                {   // cfg2: even tokens
                    int s2 = n0 >> 12, j2 = (n0 & 4095) >> 1;
                    u16x8 e;
                    #pragma unroll
                    for (int i = 0; i < 8; i++) e[i] = lT[d_l * 72 + q * 16 + 2 * i];
                    u16* dst = (u16*)Vtt2 + ((size_t)(bL * 2 + s2) * 64 + (j2 >> 5)) * 8192
                               + (size_t)dg * 32 + q * 8;
                    *(u16x8*)dst = e;
                }
                {   // cfg4: tokens %4==0
                    int j4 = n0 >> 2;
                    u16x4 e;
                    #pragma unroll
                    for (int i = 0; i < 4; i++) e[i] = lT[d_l * 72 + q * 16 + 4 * i];
                    u16* dst = (u16*)Vtt4 + ((size_t)bL * 64 + (j4 >> 5)) * 8192
                               + (size_t)dg * 32 + (j4 & 31) + q * 4;
                    *(u16x4*)dst = e;
                }
            }
        }
    }
}

// ---------------------------------------------------------------- attention
// Block = 4 waves x 32 q-rows = 128 q-rows of one (seg, qt, key-chunk) item.
// 32x32x16 MFMA.  K fragments are read DIRECTLY FROM GLOBAL (L2-resident,
// ~8x reuse across blocks) -- this moves half the LDS-pipe traffic (which was
// the dominant pipe: all 4 waves re-read identical K/V tiles) onto the idle
// VMEM pipe.  V tiles (32 keys) stay LDS-staged via global_load_lds,
// double-buffered, ONE barrier per tile: after the head vmcnt(0)+barrier
// (V(kt) landed for all waves, everyone done reading buf^1), tile kt+1 is
// DMA'd into buf^1 while tile kt computes.
//   V LDS byte addr = keychunk*4096 + d*16      (keychunk = k/8, 0..3)
// Cross-lane ops: verified __shfl_xor forms only (permlane poisoned r4/r5).
// Key-chunks ci=1 (keys 1024..) write partial O/D merged by finalize.
__global__ __launch_bounds__(256, 2)
void attn(const bf16* __restrict__ Qb, const bf16* __restrict__ Kb,
          const bf16* __restrict__ Vtt1, const bf16* __restrict__ Vtt2,
          const bf16* __restrict__ Vtt4,
          float* __restrict__ O1, float* __restrict__ O2, float* __restrict__ O4,
          float* __restrict__ D1, float* __restrict__ D2, float* __restrict__ D4,
          float* __restrict__ PO, float* __restrict__ PD,
          int* __restrict__ cnt) {
    __shared__ __align__(16) char V_l[2][16384];
    __shared__ int item_s;

    const int tid = threadIdx.x, wv = tid >> 6, lane = tid & 63;
    const int l31 = lane & 31, hi = lane >> 5;

    for (;;) {
        __syncthreads();
        if (tid == 0) item_s = atomicAdd(cnt, 1);
        __syncthreads();
        const int item = item_s;
        if (item >= 672) break;

        const unsigned e = g_items[item / 28];
        const int seg = item % 28;
        const int qt  = e & 15;
        const int ci  = (e >> 4) & 1;
        const int kt0 = ci << 5;
        const int kt1 = e >> 5;

        int lr, ss, b;
        if (seg < 16)      { lr = 0; ss = seg >> 2;        b = seg & 3;        }
        else if (seg < 24) { lr = 1; ss = (seg - 16) >> 2; b = (seg - 16) & 3; }
        else               { lr = 2; ss = 0;               b = seg - 24;       }
        const int rr = 1 << lr;
        const size_t base = (size_t)b * 8192 + (size_t)ss * (2048 << lr);
        const size_t pbase = (size_t)b * (8192 >> lr) + (size_t)ss * 2048;
        const int segi = (lr == 0) ? (b * 4 + ss) : (lr == 1) ? (b * 2 + ss) : b;
        const u16* Vseg = (const u16*)((lr == 0) ? Vtt1 : (lr == 1) ? Vtt2 : Vtt4)
                          + (size_t)segi * 524288;                  // [64 kt][256 d][32 k]
        float* Op = (lr == 0) ? O1 : (lr == 1) ? O2 : O4;
        float* Dp = (lr == 0) ? D1 : (lr == 1) ? D2 : D4;

        const int ql = qt * 128 + wv * 32 + l31;      // segment-local q row
        const u16* Kp = (const u16*)Kb + base * 256;

        // Q fragments: B-layout, n = q = l31, k = ks*16 + hi*8 + j
        bf16x8 qf[16];
        {
            const bf16* qp = Qb + (base + (size_t)ql * rr) * 256 + hi * 8;
            #pragma unroll
            for (int ks = 0; ks < 16; ks++) qf[ks] = *(const bf16x8*)(qp + ks * 16);
        }

        // stage V tile t into buffer bs (4 global_load_lds per wave)
        auto stageV = [&](int t, int bs) {
            #pragma unroll
            for (int i = 0; i < 4; i++) {
                const u16* src = Vseg + (size_t)t * 8192 + (size_t)tid * 32 + i * 8;
                load_lds16(src, &V_l[bs][i * 4096 + wv * 1024]);
            }
        };

        f32x16 o[8] = {};
        float m_run = -1e30f, l_run = 0.f;

        stageV(kt0, 0);

        const int dtile = 4 * qt + wv;          // this wave's diagonal tile
        for (int kt = kt0; kt < kt1; kt++) {
            const int buf = (kt - kt0) & 1;
            asm volatile("s_waitcnt vmcnt(0)" ::: "memory");
            __builtin_amdgcn_s_barrier();
            __builtin_amdgcn_sched_barrier(0);
            if (kt + 1 < kt1) stageV(kt + 1, buf ^ 1);

            if (kt <= dtile) {                  // skip fully-masked tiles
                const char* Vbl = V_l[buf];

                // S^T = K Q^T : A = K rows (m = key, straight from global/L2)
                // global K frag: key = kt*32 + l31 (x rr), d = ks*16 + hi*8 + j
                const bf16* krp = (const bf16*)(Kp + (size_t)((kt * 32 + l31) * rr) * 256 + hi * 8);
                f32x16 sv = {};
                __builtin_amdgcn_s_setprio(1);
                #pragma unroll
                for (int ks = 0; ks < 16; ks++) {
                    bf16x8 kf = *(const bf16x8*)(krp + ks * 16);
                    sv = MFMA32(kf, qf[ks], sv);
                }
                __builtin_amdgcn_s_setprio(0);

                // causal mask (diagonal tile only) + row max
                float mx = -1e30f;
                const bool diag = (kt == dtile);
                #pragma unroll
                for (int r = 0; r < 16; r++) {
                    float v = sv[r];
                    if (diag) {
                        int key = kt * 32 + (r & 3) + 8 * (r >> 2) + 4 * hi;
                        if (key > ql) v = -1e30f;
                        sv[r] = v;
                    }
                    mx = fmaxf(mx, v);
                }
                mx = fmaxf(mx, __shfl_xor(mx, 32));   // combine wave halves

                // deferred rescale (threshold 12 in log2 domain ~ e^8.3)
                if (__any(mx > m_run + 12.0f)) {
                    float mnew = fmaxf(m_run, mx);
                    float fac = exp2f(m_run - mnew);
                    l_run *= fac;
                    #pragma unroll
                    for (int dg = 0; dg < 8; dg++)
                        #pragma unroll
                        for (int r = 0; r < 16; r++) o[dg][r] *= fac;
                    m_run = mnew;
                }

                float rs = 0.f;
                #pragma unroll
                for (int r = 0; r < 16; r++) {
                    float e2 = exp2f(sv[r] - m_run);
                    sv[r] = e2;
                    rs += e2;
                }
                rs += __shfl_xor(rs, 32);
                l_run += rs;

                // P^T bf16 words: pk[2a+b] (lane half h) = keys {8a+4h+2b, +1}
                unsigned pk[8];
                #pragma unroll
                for (int rq = 0; rq < 4; rq++) {
                    pk[2 * rq]     = pack2(sv[4 * rq],     sv[4 * rq + 1]);
                    pk[2 * rq + 1] = pack2(sv[4 * rq + 2], sv[4 * rq + 3]);
                }
                // B-fragment step st needs keys st*16 + hi*8 + (0..7)
                // (verified shfl_xor redistribution, identical to round-3 pass)
                #pragma unroll
                for (int st = 0; st < 2; st++) {
                    unsigned p0 = pk[4 * st],     p1 = pk[4 * st + 1];
                    unsigned p2 = pk[4 * st + 2], p3 = pk[4 * st + 3];
                    unsigned s0 = (unsigned)__shfl_xor((int)p0, 32);
                    unsigned s1 = (unsigned)__shfl_xor((int)p1, 32);
                    unsigned s2 = (unsigned)__shfl_xor((int)p2, 32);
                    unsigned s3 = (unsigned)__shfl_xor((int)p3, 32);
                    union { unsigned u[4]; bf16x8 v; } pb;
                    pb.u[0] = hi ? s2 : p0;
                    pb.u[1] = hi ? s3 : p1;
                    pb.u[2] = hi ? p2 : s0;
                    pb.u[3] = hi ? p3 : s1;
                    // O^T += V^T P^T : A = V^T rows (m = d)
                    __builtin_amdgcn_s_setprio(1);
                    #pragma unroll
                    for (int dg = 0; dg < 8; dg++) {
                        bf16x8 vf = *(const bf16x8*)(Vbl + (st * 2 + hi) * 4096 + dg * 512 + l31 * 16);
                        o[dg] = MFMA32(vf, pb.v, o[dg]);
                    }
                    __builtin_amdgcn_s_setprio(0);
                }
            }
        }

        // epilogue: normalized partial + denom (chunk 0 -> main, chunk 1 -> P)
        float invl = 1.0f / l_run;
        size_t prow;
        float *obase, *dbase;
        if (ci == 0) { prow = pbase + (size_t)ql;                    obase = Op; dbase = Dp; }
        else         { prow = (size_t)seg * 1024 + (size_t)(ql - 1024); obase = PO; dbase = PD; }
        if (hi == 0) dbase[prow] = l_run * exp2f(m_run);
        float* orow = obase + prow * 256 + hi * 4;
        #pragma unroll
        for (int dg = 0; dg < 8; dg++)
            #pragma unroll
            for (int rq = 0; rq < 4; rq++) {
                f32x4 v;
                v[0] = o[dg][4 * rq]     * invl;
                v[1] = o[dg][4 * rq + 1] * invl;
                v[2] = o[dg][4 * rq + 2] * invl;
                v[3] = o[dg][4 * rq + 3] * invl;
                *(f32x4*)(orow + dg * 32 + rq * 8) = v;
            }
    }
}

// ---------------------------------------------------------------- finalize
// out = sum(O_c * d_c) / sum(d_c) over {cfg1, cfg2, cfg4, key-chunk partials}.
__global__ void finalize(float* __restrict__ out, const float* __restrict__ O2,
                         const float* __restrict__ O4,
                         const float* __restrict__ D1, const float* __restrict__ D2,
                         const float* __restrict__ D4,
                         const float* __restrict__ PO, const float* __restrict__ PD) {
    int g = blockIdx.x * 256 + threadIdx.x;     // 32768 tokens * 64 chunks
    int t = g >> 6, dc = (g & 63) * 4;
    int b = t >> 13, n = t & 8191;
    float d1 = D1[t];
    float4 o1 = *(float4*)(out + (size_t)t * 256 + dc);
    float ax = o1.x * d1, ay = o1.y * d1, az = o1.z * d1, aw = o1.w * d1;
    float den = d1;
    {   // cfg1 key-chunk partial
        int j1 = n & 2047;
        if (j1 >= 1024) {
            size_t pp = (size_t)(4 * (n >> 11) + b) * 1024 + (j1 - 1024);
            float dp = PD[pp];
            const float4 op = *(const float4*)(PO + pp * 256 + dc);
            ax += op.x * dp; ay += op.y * dp; az += op.z * dp; aw += op.w * dp;
            den += dp;
        }
    }
    if ((n & 1) == 0) {
        int s2 = n >> 12, j2 = (n & 4095) >> 1;
        int pos2 = b * 4096 + s2 * 2048 + j2;
        float d2 = D2[pos2];
        const float4 o2 = *(const float4*)(O2 + (size_t)pos2 * 256 + dc);
        ax += o2.x * d2; ay += o2.y * d2; az += o2.z * d2; aw += o2.w * d2;
        den += d2;
        if (j2 >= 1024) {
            size_t pp = (size_t)(16 + 4 * s2 + b) * 1024 + (j2 - 1024);
            float dp = PD[pp];
            const float4 op = *(const float4*)(PO + pp * 256 + dc);
            ax += op.x * dp; ay += op.y * dp; az += op.z * dp; aw += op.w * dp;
            den += dp;
        }
    }
    if ((n & 3) == 0) {
        int j4 = n >> 2;
        int pos4 = b * 2048 + j4;
        float d4 = D4[pos4];
        const float4 o4 = *(const float4*)(O4 + (size_t)pos4 * 256 + dc);
        ax += o4.x * d4; ay += o4.y * d4; az += o4.z * d4; aw += o4.w * d4;
        den += d4;
        if (j4 >= 1024) {
            size_t pp = (size_t)(24 + b) * 1024 + (j4 - 1024);
            float dp = PD[pp];
            const float4 op = *(const float4*)(PO + pp * 256 + dc);
            ax += op.x * dp; ay += op.y * dp; az += op.z * dp; aw += op.w * dp;
            den += dp;
        }
    }
    float inv = 1.0f / den;
    float4 r; r.x = ax * inv; r.y = ay * inv; r.z = az * inv; r.w = aw * inv;
    *(float4*)(out + (size_t)t * 256 + dc) = r;
}

// ---------------------------------------------------------------- launch
extern "C" void kernel_launch(void* const* d_in, const int* in_sizes, int n_in,
                              void* d_out, int out_size, void* d_ws, size_t ws_size,
                              hipStream_t stream) {
    const float* x  = (const float*)d_in[0];
    const float* Wq = (const float*)d_in[1];
    const float* Wk = (const float*)d_in[2];
    const float* Wv = (const float*)d_in[3];
    float* out = (float*)d_out;

    char* ws = (char*)d_ws;
    bf16* Qb   = (bf16*)(ws);                        // 16 MB
    bf16* Kb   = (bf16*)(ws + 16777216);             // 16 MB
    bf16* Vtt1 = (bf16*)(ws + 33554432);             // 16 MB  [16 seg][64 kt][256][32]
    bf16* Vtt2 = (bf16*)(ws + 50331648);             //  8 MB
    bf16* Vtt4 = (bf16*)(ws + 58720256);             //  4 MB
    bf16* Wbt  = (bf16*)(ws + 62914560);             // 384 KB
    float* O2  = (float*)(ws + 63307776);            // 16 MB
    float* O4  = (float*)(ws + 80084992);            //  8 MB
    float* D1  = (float*)(ws + 88473600);            // 128 KB
    float* D2  = (float*)(ws + 88604672);            //  64 KB
    float* D4  = (float*)(ws + 88670208);            //  32 KB
    int*   cnt = (int*)(ws + 88702976);              //  4 B work-ticket
    float* PO  = (float*)(ws + 88703232);            // 28 MB  [28 seg][1024 row][256]
    float* PD  = (float*)(ws + 118063360);           // 112 KB [28 seg][1024 row]

    cvt_w<<<768, 256, 0, stream>>>(Wq, Wk, Wv, Wbt, cnt);
    qkv_gemm<<<512, 256, 0, stream>>>(x, Wbt, Qb, Kb, Vtt1, Vtt2, Vtt4);
    attn<<<512, 256, 0, stream>>>(Qb, Kb, Vtt1, Vtt2, Vtt4, out, O2, O4,
                                  D1, D2, D4, PO, PD, cnt);
    finalize<<<8192, 256, 0, stream>>>(out, O2, O4, D1, D2, D4, PO, PD);
}

// Round 8
// 236.747 us; speedup vs baseline: 1.6213x; 1.6213x over previous
//
#include <hip/hip_runtime.h>
#include <hip/hip_bf16.h>

typedef __bf16 bf16;
typedef unsigned short u16;
typedef bf16 bf16x8 __attribute__((ext_vector_type(8)));
typedef bf16 bf16x2 __attribute__((ext_vector_type(2)));
typedef u16  u16x8  __attribute__((ext_vector_type(8)));
typedef u16  u16x4  __attribute__((ext_vector_type(4)));
typedef float f32x4 __attribute__((ext_vector_type(4)));
typedef float f32x16 __attribute__((ext_vector_type(16)));

#define MFMA16(a,b,c) __builtin_amdgcn_mfma_f32_16x16x32_bf16((a),(b),(c),0,0,0)
#define MFMA32(a,b,c) __builtin_amdgcn_mfma_f32_32x32x16_bf16((a),(b),(c),0,0,0)
#define QSCALE 0.09016844005625f   // (1/16) * log2(e)

__device__ inline unsigned pack2(float a, float b) {
    bf16x2 t; t[0] = (bf16)a; t[1] = (bf16)b;
    return __builtin_bit_cast(unsigned, t);
}

// async global->LDS, 16B per lane; LDS dest must be wave-uniform base + lane*16
__device__ __forceinline__ void load_lds16(const void* g, void* l) {
    __builtin_amdgcn_global_load_lds(
        (const __attribute__((address_space(1))) unsigned*)g,
        (__attribute__((address_space(3))) unsigned*)l, 16, 0, 0);
}

// Work items, heavy-first (hardware dispatches blockIdx roughly in order ->
// LPT schedule; perf heuristic only).  qt>=8 items split into two key-chunks:
// ci=0 -> tiles [0,32), ci=1 -> tiles [32, 4*(qt+1)).  672 = 24*28 total.
// pack: qt | ci<<4 | kt1<<5   (kt0 = ci*32)
__device__ const unsigned short g_items[24] = {
    (unsigned short)(15 | (0u<<4) | (32u<<5)),
    (unsigned short)(14 | (0u<<4) | (32u<<5)),
    (unsigned short)(13 | (0u<<4) | (32u<<5)),
    (unsigned short)(12 | (0u<<4) | (32u<<5)),
    (unsigned short)(11 | (0u<<4) | (32u<<5)),
    (unsigned short)(10 | (0u<<4) | (32u<<5)),
    (unsigned short)( 9 | (0u<<4) | (32u<<5)),
    (unsigned short)( 8 | (0u<<4) | (32u<<5)),
    (unsigned short)(15 | (1u<<4) | (64u<<5)),
    (unsigned short)( 7 | (0u<<4) | (32u<<5)),
    (unsigned short)(14 | (1u<<4) | (60u<<5)),
    (unsigned short)( 6 | (0u<<4) | (28u<<5)),
    (unsigned short)(13 | (1u<<4) | (56u<<5)),
    (unsigned short)( 5 | (0u<<4) | (24u<<5)),
    (unsigned short)(12 | (1u<<4) | (52u<<5)),
    (unsigned short)( 4 | (0u<<4) | (20u<<5)),
    (unsigned short)(11 | (1u<<4) | (48u<<5)),
    (unsigned short)( 3 | (0u<<4) | (16u<<5)),
    (unsigned short)(10 | (1u<<4) | (44u<<5)),
    (unsigned short)( 2 | (0u<<4) | (12u<<5)),
    (unsigned short)( 9 | (1u<<4) | (40u<<5)),
    (unsigned short)( 1 | (0u<<4) | ( 8u<<5)),
    (unsigned short)( 8 | (1u<<4) | (36u<<5)),
    (unsigned short)( 0 | (0u<<4) | ( 4u<<5)),
};

// W (f32 [c][d]) -> bf16 transposed [which][d][c]
__global__ void cvt_w(const float* __restrict__ Wq, const float* __restrict__ Wk,
                      const float* __restrict__ Wv, bf16* __restrict__ Wbt) {
    int idx = blockIdx.x * 256 + threadIdx.x;
    int which = idx >> 16;
    int rem = idx & 65535;
    int c = rem >> 8, d = rem & 255;
    const float* W = (which == 0) ? Wq : (which == 1) ? Wk : Wv;
    Wbt[(size_t)which * 65536 + d * 256 + c] = (bf16)W[c * 256 + d];
}

// ---------------------------------------------------------------- QKV GEMM
// block = 64 tokens x full 256 d; q/k/v fused.  x-tile staged ONCE into
// lA[2] (identical across q/k/v, r7-verified).  W tiles LDS-staged with the
// conflict-free 136-pad (r6-verified read pattern), DOUBLE-BUFFERED: one
// barrier per tile, stage(t+1) overlaps compute(t).  Barriers 78 -> 49.
__global__ __launch_bounds__(256, 2)
void qkv_gemm(const float* __restrict__ x, const bf16* __restrict__ Wbt,
              bf16* __restrict__ Qb, bf16* __restrict__ Kb,
              bf16* __restrict__ Vtt1, bf16* __restrict__ Vtt2, bf16* __restrict__ Vtt4) {
    __shared__ __align__(16) u16 lA[2][64 * 136];   // [kh][tok][col]
    __shared__ __align__(16) u16 lB[2][64 * 136];   // W double buffer
    __shared__ __align__(16) u16 lT[64 * 72];       // epilogue staging
    int mt = blockIdx.x;
    int tid = threadIdx.x, wv = tid >> 6, lane = tid & 63;
    int l15 = lane & 15, quad = lane >> 4;

    const float* Ax = x + (size_t)(mt * 64) * 256;
    int row = tid >> 2, c0 = (tid & 3) * 32;

    // stage A (both halves); the t-loop head barrier covers these writes
    #pragma unroll
    for (int kh = 0; kh < 2; kh++)
        #pragma unroll
        for (int i = 0; i < 4; i++) {
            float4 f0 = *(const float4*)(Ax + row * 256 + kh * 128 + c0 + i * 8);
            float4 f1 = *(const float4*)(Ax + row * 256 + kh * 128 + c0 + i * 8 + 4);
            bf16x8 v;
            v[0] = (bf16)f0.x; v[1] = (bf16)f0.y; v[2] = (bf16)f0.z; v[3] = (bf16)f0.w;
            v[4] = (bf16)f1.x; v[5] = (bf16)f1.y; v[6] = (bf16)f1.z; v[7] = (bf16)f1.w;
            *(bf16x8*)((bf16*)lA[kh] + row * 136 + c0 + i * 8) = v;
        }

    // stage W tile t = kh*4 + nt of matrix Bw into buffer bs
    auto stageW = [&](const bf16* Bw, int t, int bs) {
        int kh = t >> 2, nt = t & 3;
        #pragma unroll
        for (int i = 0; i < 4; i++)
            *(bf16x8*)((bf16*)lB[bs] + row * 136 + c0 + i * 8) =
                *(const bf16x8*)(Bw + (size_t)(nt * 64 + row) * 256 + kh * 128 + c0 + i * 8);
    };

    for (int which = 0; which < 3; which++) {
        f32x4 acc[4][4] = {};
        const bf16* Bw = Wbt + (size_t)which * 65536;
        stageW(Bw, 0, 0);
        for (int t = 0; t < 8; t++) {
            __syncthreads();
            if (t + 1 < 8) stageW(Bw, t + 1, (t + 1) & 1);
            int kh = t >> 2, nt = t & 3;
            #pragma unroll
            for (int ks = 0; ks < 4; ks++) {
                bf16x8 a = *(const bf16x8*)((bf16*)lA[kh] + (wv * 16 + l15) * 136 + ks * 32 + quad * 8);
                #pragma unroll
                for (int ns = 0; ns < 4; ns++) {
                    bf16x8 b2 = *(const bf16x8*)((bf16*)lB[t & 1] + (ns * 16 + l15) * 136 + ks * 32 + quad * 8);
                    acc[nt][ns] = MFMA16(a, b2, acc[nt][ns]);
                }
            }
        }

        // Epilogue per nt, staged through lT for coalesced stores (r6 layout).
        float sc = (which == 0) ? QSCALE : 1.0f;
        for (int nt = 0; nt < 4; nt++) {
            __syncthreads();
            if (which < 2) {
                // layout [tok][col]
                #pragma unroll
                for (int ns = 0; ns < 4; ns++)
                    #pragma unroll
                    for (int r = 0; r < 4; r++) {
                        bf16 v = (bf16)(acc[nt][ns][r] * sc);
                        lT[(wv * 16 + quad * 4 + r) * 72 + ns * 16 + l15] = *(u16*)&v;
                    }
                __syncthreads();
                bf16* outp = (which == 0) ? Qb : Kb;
                int tokl = tid >> 2, ch = tid & 3;
                u16x8 v0 = *(u16x8*)(lT + tokl * 72 + ch * 16);
                u16x8 v1 = *(u16x8*)(lT + tokl * 72 + ch * 16 + 8);
                u16* dst = (u16*)outp + (size_t)(mt * 64 + tokl) * 256 + nt * 64 + ch * 16;
                *(u16x8*)dst = v0;
                *(u16x8*)(dst + 8) = v1;
            } else {
                // layout [col d][tok]
                #pragma unroll
                for (int ns = 0; ns < 4; ns++)
                    #pragma unroll
                    for (int r = 0; r < 4; r++) {
                        bf16 v = (bf16)acc[nt][ns][r];
                        lT[(ns * 16 + l15) * 72 + wv * 16 + quad * 4 + r] = *(u16*)&v;
                    }
                __syncthreads();
                int gtok = mt * 64;
                int bL = gtok >> 13, n0 = gtok & 8191;
                int d_l = tid >> 2, q = tid & 3;
                int dg = nt * 64 + d_l;
                {   // cfg1
                    int s1 = n0 >> 11, j1 = n0 & 2047;
                    u16* dst = (u16*)Vtt1 + ((size_t)(bL * 4 + s1) * 64 + (j1 >> 5) + (q >> 1)) * 8192
                               + (size_t)dg * 32 + (q & 1) * 16;
                    u16x8 a0 = *(u16x8*)(lT + d_l * 72 + q * 16);
                    u16x8 a1 = *(u16x8*)(lT + d_l * 72 + q * 16 + 8);
                    *(u16x8*)dst = a0; *(u16x8*)(dst + 8) = a1;
                }
                {   // cfg2: even tokens
                    int s2 = n0 >> 12, j2 = (n0 & 4095) >> 1;
                    u16x8 e;
                    #pragma unroll
                    for (int i = 0; i < 8; i++) e[i] = lT[d_l * 72 + q * 16 + 2 * i];
                    u16* dst = (u16*)Vtt2 + ((size_t)(bL * 2 + s2) * 64 + (j2 >> 5)) * 8192
                               + (size_t)dg * 32 + q * 8;
                    *(u16x8*)dst = e;
                }
                {   // cfg4: tokens %4==0
                    int j4 = n0 >> 2;
                    u16x4 e;
                    #pragma unroll
                    for (int i = 0; i < 4; i++) e[i] = lT[d_l * 72 + q * 16 + 4 * i];
                    u16* dst = (u16*)Vtt4 + ((size_t)bL * 64 + (j4 >> 5)) * 8192
                               + (size_t)dg * 32 + (j4 & 31) + q * 4;
                    *(u16x4*)dst = e;
                }
            }
        }
    }
}

// ---------------------------------------------------------------- attention
// One block per item (grid = 672, heavy items first).  Block = 4 waves x 32
// q-rows = 128 q-rows of one (seg, qt, key-chunk) item.  32x32x16 MFMA; K/V
// tiles (32 keys) double-buffered in LDS via global_load_lds; ONE barrier per
// tile: after the head vmcnt(0)+barrier, tile kt+1 is DMA'd into buf^1 while
// tile kt computes.  Chunk-transposed LDS layouts keep every ds_read_b128
// conflict-free:
//   K LDS byte addr = dchunk*512  + keyrow*16   (dchunk = d/8, 0..31)
//   V LDS byte addr = keychunk*4096 + d*16      (keychunk = k/8, 0..3)
// Cross-lane ops: verified __shfl_xor forms only (permlane poisoned r4/r5;
// K-from-global poisoned r7: 32 cache lines per wave-load on the QK path).
// Key-chunks ci=1 (keys 1024..) write partial O/D merged by finalize.
__global__ __launch_bounds__(256, 2)
void attn(const bf16* __restrict__ Qb, const bf16* __restrict__ Kb,
          const bf16* __restrict__ Vtt1, const bf16* __restrict__ Vtt2,
          const bf16* __restrict__ Vtt4,
          float* __restrict__ O1, float* __restrict__ O2, float* __restrict__ O4,
          float* __restrict__ D1, float* __restrict__ D2, float* __restrict__ D4,
          float* __restrict__ PO, float* __restrict__ PD) {
    __shared__ __align__(16) char K_l[2][16384];
    __shared__ __align__(16) char V_l[2][16384];

    const int tid = threadIdx.x, wv = tid >> 6, lane = tid & 63;
    const int l31 = lane & 31, hi = lane >> 5;

    const int item = (int)blockIdx.x;
    const unsigned e = g_items[item / 28];
    const int seg = item % 28;
    const int qt  = e & 15;
    const int ci  = (e >> 4) & 1;
    const int kt0 = ci << 5;
    const int kt1 = e >> 5;

    int lr, ss, b;
    if (seg < 16)      { lr = 0; ss = seg >> 2;        b = seg & 3;        }
    else if (seg < 24) { lr = 1; ss = (seg - 16) >> 2; b = (seg - 16) & 3; }
    else               { lr = 2; ss = 0;               b = seg - 24;       }
    const int rr = 1 << lr;
    const size_t base = (size_t)b * 8192 + (size_t)ss * (2048 << lr);
    const size_t pbase = (size_t)b * (8192 >> lr) + (size_t)ss * 2048;
    const int segi = (lr == 0) ? (b * 4 + ss) : (lr == 1) ? (b * 2 + ss) : b;
    const u16* Vseg = (const u16*)((lr == 0) ? Vtt1 : (lr == 1) ? Vtt2 : Vtt4)
                      + (size_t)segi * 524288;                  // [64 kt][256 d][32 k]
    float* Op = (lr == 0) ? O1 : (lr == 1) ? O2 : O4;
    float* Dp = (lr == 0) ? D1 : (lr == 1) ? D2 : D4;

    const int ql = qt * 128 + wv * 32 + l31;      // segment-local q row
    const u16* Kp = (const u16*)Kb + base * 256;

    // Q fragments: B-layout, n = q = l31, k = ks*16 + hi*8 + j
    bf16x8 qf[16];
    {
        const bf16* qp = Qb + (base + (size_t)ql * rr) * 256 + hi * 8;
        #pragma unroll
        for (int ks = 0; ks < 16; ks++) qf[ks] = *(const bf16x8*)(qp + ks * 16);
    }

    // stage tile t into buffer bs (8 global_load_lds per wave)
    auto stage = [&](int t, int bs) {
        #pragma unroll
        for (int i = 0; i < 4; i++) {
            const u16* src = Kp + (size_t)((t * 32 + (tid & 31)) * rr) * 256
                             + (i * 8 + (tid >> 5)) * 8;
            load_lds16(src, &K_l[bs][i * 4096 + wv * 1024]);
        }
        #pragma unroll
        for (int i = 0; i < 4; i++) {
            const u16* src = Vseg + (size_t)t * 8192 + (size_t)tid * 32 + i * 8;
            load_lds16(src, &V_l[bs][i * 4096 + wv * 1024]);
        }
    };

    f32x16 o[8] = {};
    float m_run = -1e30f, l_run = 0.f;

    stage(kt0, 0);

    const int dtile = 4 * qt + wv;          // this wave's diagonal tile
    for (int kt = kt0; kt < kt1; kt++) {
        const int buf = (kt - kt0) & 1;
        asm volatile("s_waitcnt vmcnt(0)" ::: "memory");
        __builtin_amdgcn_s_barrier();
        __builtin_amdgcn_sched_barrier(0);
        if (kt + 1 < kt1) stage(kt + 1, buf ^ 1);

        if (kt <= dtile) {                  // skip fully-masked tiles
            const char* Kbl = K_l[buf];
            const char* Vbl = V_l[buf];

            // S^T = K Q^T : A = K rows (m = key), B = Q (n = q)
            f32x16 sv = {};
            __builtin_amdgcn_s_setprio(1);
            #pragma unroll
            for (int ks = 0; ks < 16; ks++) {
                bf16x8 kf = *(const bf16x8*)(Kbl + ks * 1024 + hi * 512 + l31 * 16);
                sv = MFMA32(kf, qf[ks], sv);
            }
            __builtin_amdgcn_s_setprio(0);

            // causal mask (diagonal tile only) + row max
            float mx = -1e30f;
            const bool diag = (kt == dtile);
            #pragma unroll
            for (int r = 0; r < 16; r++) {
                float v = sv[r];
                if (diag) {
                    int key = kt * 32 + (r & 3) + 8 * (r >> 2) + 4 * hi;
                    if (key > ql) v = -1e30f;
                    sv[r] = v;
                }
                mx = fmaxf(mx, v);
            }
            mx = fmaxf(mx, __shfl_xor(mx, 32));   // combine wave halves

            // deferred rescale (threshold 12 in log2 domain ~ e^8.3)
            if (__any(mx > m_run + 12.0f)) {
                float mnew = fmaxf(m_run, mx);
                float fac = exp2f(m_run - mnew);
                l_run *= fac;
                #pragma unroll
                for (int dg = 0; dg < 8; dg++)
                    #pragma unroll
                    for (int r = 0; r < 16; r++) o[dg][r] *= fac;
                m_run = mnew;
            }

            float rs = 0.f;
            #pragma unroll
            for (int r = 0; r < 16; r++) {
                float e2 = exp2f(sv[r] - m_run);
                sv[r] = e2;
                rs += e2;
            }
            rs += __shfl_xor(rs, 32);
            l_run += rs;

            // P^T bf16 words: pk[2a+b] (lane half h) = keys {8a+4h+2b, +1}
            unsigned pk[8];
            #pragma unroll
            for (int rq = 0; rq < 4; rq++) {
                pk[2 * rq]     = pack2(sv[4 * rq],     sv[4 * rq + 1]);
                pk[2 * rq + 1] = pack2(sv[4 * rq + 2], sv[4 * rq + 3]);
            }
            // B-fragment step st needs keys st*16 + hi*8 + (0..7)
            // (verified shfl_xor redistribution, identical to round-3 pass)
            #pragma unroll
            for (int st = 0; st < 2; st++) {
                unsigned p0 = pk[4 * st],     p1 = pk[4 * st + 1];
                unsigned p2 = pk[4 * st + 2], p3 = pk[4 * st + 3];
                unsigned s0 = (unsigned)__shfl_xor((int)p0, 32);
                unsigned s1 = (unsigned)__shfl_xor((int)p1, 32);
                unsigned s2 = (unsigned)__shfl_xor((int)p2, 32);
                unsigned s3 = (unsigned)__shfl_xor((int)p3, 32);
                union { unsigned u[4]; bf16x8 v; } pb;
                pb.u[0] = hi ? s2 : p0;
                pb.u[1] = hi ? s3 : p1;
                pb.u[2] = hi ? p2 : s0;
                pb.u[3] = hi ? p3 : s1;
                // O^T += V^T P^T : A = V^T rows (m = d)
                __builtin_amdgcn_s_setprio(1);
                #pragma unroll
                for (int dg = 0; dg < 8; dg++) {
                    bf16x8 vf = *(const bf16x8*)(Vbl + (st * 2 + hi) * 4096 + dg * 512 + l31 * 16);
                    o[dg] = MFMA32(vf, pb.v, o[dg]);
                }
                __builtin_amdgcn_s_setprio(0);
            }
        }
    }

    // epilogue: normalized partial + denom (chunk 0 -> main, chunk 1 -> P)
    float invl = 1.0f / l_run;
    size_t prow;
    float *obase, *dbase;
    if (ci == 0) { prow = pbase + (size_t)ql;                    obase = Op; dbase = Dp; }
    else         { prow = (size_t)seg * 1024 + (size_t)(ql - 1024); obase = PO; dbase = PD; }
    if (hi == 0) dbase[prow] = l_run * exp2f(m_run);
    float* orow = obase + prow * 256 + hi * 4;
    #pragma unroll
    for (int dg = 0; dg < 8; dg++)
        #pragma unroll
        for (int rq = 0; rq < 4; rq++) {
            f32x4 v;
            v[0] = o[dg][4 * rq]     * invl;
            v[1] = o[dg][4 * rq + 1] * invl;
            v[2] = o[dg][4 * rq + 2] * invl;
            v[3] = o[dg][4 * rq + 3] * invl;
            *(f32x4*)(orow + dg * 32 + rq * 8) = v;
        }
}

// ---------------------------------------------------------------- finalize
// out = sum(O_c * d_c) / sum(d_c) over {cfg1, cfg2, cfg4, key-chunk partials}.
__global__ void finalize(float* __restrict__ out, const float* __restrict__ O2,
                         const float* __restrict__ O4,
                         const float* __restrict__ D1, const float* __restrict__ D2,
                         const float* __restrict__ D4,
                         const float* __restrict__ PO, const float* __restrict__ PD) {
    int g = blockIdx.x * 256 + threadIdx.x;     // 32768 tokens * 64 chunks
    int t = g >> 6, dc = (g & 63) * 4;
    int b = t >> 13, n = t & 8191;
    float d1 = D1[t];
    float4 o1 = *(float4*)(out + (size_t)t * 256 + dc);
    float ax = o1.x * d1, ay = o1.y * d1, az = o1.z * d1, aw = o1.w * d1;
    float den = d1;
    {   // cfg1 key-chunk partial
        int j1 = n & 2047;
        if (j1 >= 1024) {
            size_t pp = (size_t)(4 * (n >> 11) + b) * 1024 + (j1 - 1024);
            float dp = PD[pp];
            const float4 op = *(const float4*)(PO + pp * 256 + dc);
            ax += op.x * dp; ay += op.y * dp; az += op.z * dp; aw += op.w * dp;
            den += dp;
        }
    }
    if ((n & 1) == 0) {
        int s2 = n >> 12, j2 = (n & 4095) >> 1;
        int pos2 = b * 4096 + s2 * 2048 + j2;
        float d2 = D2[pos2];
        const float4 o2 = *(const float4*)(O2 + (size_t)pos2 * 256 + dc);
        ax += o2.x * d2; ay += o2.y * d2; az += o2.z * d2; aw += o2.w * d2;
        den += d2;
        if (j2 >= 1024) {
            size_t pp = (size_t)(16 + 4 * s2 + b) * 1024 + (j2 - 1024);
            float dp = PD[pp];
            const float4 op = *(const float4*)(PO + pp * 256 + dc);
            ax += op.x * dp; ay += op.y * dp; az += op.z * dp; aw += op.w * dp;
            den += dp;
        }
    }
    if ((n & 3) == 0) {
        int j4 = n >> 2;
        int pos4 = b * 2048 + j4;
        float d4 = D4[pos4];
        const float4 o4 = *(const float4*)(O4 + (size_t)pos4 * 256 + dc);
        ax += o4.x * d4; ay += o4.y * d4; az += o4.z * d4; aw += o4.w * d4;
        den += d4;
        if (j4 >= 1024) {
            size_t pp = (size_t)(24 + b) * 1024 + (j4 - 1024);
            float dp = PD[pp];
            const float4 op = *(const float4*)(PO + pp * 256 + dc);
            ax += op.x * dp; ay += op.y * dp; az += op.z * dp; aw += op.w * dp;
            den += dp;
        }
    }
    float inv = 1.0f / den;
    float4 r; r.x = ax * inv; r.y = ay * inv; r.z = az * inv; r.w = aw * inv;
    *(float4*)(out + (size_t)t * 256 + dc) = r;
}

// ---------------------------------------------------------------- launch
extern "C" void kernel_launch(void* const* d_in, const int* in_sizes, int n_in,
                              void* d_out, int out_size, void* d_ws, size_t ws_size,
                              hipStream_t stream) {
    const float* x  = (const float*)d_in[0];
    const float* Wq = (const float*)d_in[1];
    const float* Wk = (const float*)d_in[2];
    const float* Wv = (const float*)d_in[3];
    float* out = (float*)d_out;

    char* ws = (char*)d_ws;
    bf16* Qb   = (bf16*)(ws);                        // 16 MB
    bf16* Kb   = (bf16*)(ws + 16777216);             // 16 MB
    bf16* Vtt1 = (bf16*)(ws + 33554432);             // 16 MB  [16 seg][64 kt][256][32]
    bf16* Vtt2 = (bf16*)(ws + 50331648);             //  8 MB
    bf16* Vtt4 = (bf16*)(ws + 58720256);             //  4 MB
    bf16* Wbt  = (bf16*)(ws + 62914560);             // 384 KB
    float* O2  = (float*)(ws + 63307776);            // 16 MB
    float* O4  = (float*)(ws + 80084992);            //  8 MB
    float* D1  = (float*)(ws + 88473600);            // 128 KB
    float* D2  = (float*)(ws + 88604672);            //  64 KB
    float* D4  = (float*)(ws + 88670208);            //  32 KB
    float* PO  = (float*)(ws + 88703232);            // 28 MB  [28 seg][1024 row][256]
    float* PD  = (float*)(ws + 118063360);           // 112 KB [28 seg][1024 row]

    cvt_w<<<768, 256, 0, stream>>>(Wq, Wk, Wv, Wbt);
    qkv_gemm<<<512, 256, 0, stream>>>(x, Wbt, Qb, Kb, Vtt1, Vtt2, Vtt4);
    attn<<<672, 256, 0, stream>>>(Qb, Kb, Vtt1, Vtt2, Vtt4, out, O2, O4,
                                  D1, D2, D4, PO, PD);
    finalize<<<8192, 256, 0, stream>>>(out, O2, O4, D1, D2, D4, PO, PD);
}